// Round 13
// baseline (220.747 us; speedup 1.0000x reference)
//
#include <hip/hip_runtime.h>
#include <hip/hip_bf16.h>
#include <cstdint>

// ---- problem constants ----
#define BL    2
#define LSEQ  1024
#define DMOD  1024
#define DIN   2048      // inner dim
#define NST   16        // d_state
#define DTRK  64        // dt rank
#define MR    (BL*LSEQ) // 2048 rows

// chunked scan: C chunks of T timesteps
// R13: scan is LATENCY-bound; u/z staged via glds16 so the serial t-chain is
// LDS+VALU only. R17: NEVER grid.sync (~250us/sync). R19: dt proj fused into
// p1 preamble. R20: 4 states/thread, 64 d-cols/block -> 2048 blocks (8/CU),
// half the per-t chain (221.6 -> 213.7).
#define CCH 32
#define TCH 32          // LSEQ / CCH

typedef __bf16 bf16x8 __attribute__((ext_vector_type(8)));
typedef float  f32x4  __attribute__((ext_vector_type(4)));

#if __has_builtin(__builtin_amdgcn_exp2f)
#define EXP2F(x) __builtin_amdgcn_exp2f(x)
#else
#define EXP2F(x) exp2f(x)
#endif
#define LOG2E 1.4426950408889634f

// async global->LDS, 16B per lane. LDS dest = wave-uniform base + lane*16 (m104).
__device__ __forceinline__ void glds16(const void* g, const void* l) {
    __builtin_amdgcn_global_load_lds(
        (__attribute__((address_space(1))) void*)(uintptr_t)(g),
        (__attribute__((address_space(3))) void*)(uint32_t)(uintptr_t)(l),
        16, 0, 0);
}

__device__ __forceinline__ __bf16 f2b(float f) {
    __hip_bfloat16 t = __float2bfloat16(f);
    return *(__bf16*)&t;
}

// C[M][N] = A[M][K] (bf16,lda) * B[N][K]^T (bf16,ldb), fp32 accum.
// R9: 64x128/BK=64 at 3-4 blocks/CU is the local optimum of this structure.
// R10 profile: gemm0 = 43us, MfmaUtil 17%, nothing saturated -> structural
// (MFMA floor 8us, L2 floor 11us; barrier-latency bound).
// R14/R15: LDS-coalesced epilogues + L2 super-tile decode (neutral, kept).
// R18: gemm1 ([dtin|Bm|Cm] proj) FUSED into MODE 0 isX epilogue.
// R21: gemm3 -> MODE 4: TN=128 (16 MFMA/step, 2x density) + split-K=2 with
// atomicAdd into out PRE-INITIALIZED with residual by prep. Per-CU serialized
// K-steps halve (64 -> 32).
// MODE 0 (in_proj): xproj half: conv+silu -> e0=xcb + fused proj; z half ->
//   silu -> e1=zs (LDS-coalesced).
// MODE 3: e0=float* out = acc + e1[gm*N+gn]     (retired, kept for reference)
// MODE 4: atomicAdd((float*)e0 + gm*N+gn, acc)  [out proj, split-K]
template <int MODE, int TM, int TN, int BK>
__global__ __launch_bounds__(256, 3) void gemm_bt(
    const __hip_bfloat16* __restrict__ A, int lda,
    const __hip_bfloat16* __restrict__ Bw, int ldb,
    int M, int N, int Ksl,
    void* __restrict__ e0, void* __restrict__ e1,
    const float* __restrict__ bias, const float* __restrict__ bias2,
    float* __restrict__ Af)
{
    constexpr bool FUSE = (MODE == 0);
    static_assert(!FUSE || BK == 64, "fused conv epilogue assumes BK=64");
    static_assert((MODE != 0) || TN == 128, "LDS flush assumes TN=128");
    constexpr int WM = TM / 2, WN = TN / 2;
    constexpr int MT = WM / 16, NT = WN / 16;
    constexpr int C8 = BK / 8;          // 16B chunks per row
    constexpr int RPP = 256 / C8;       // rows staged per 4KB DMA pass
    constexpr int PA = TM / RPP, PB = TN / RPP;
    __shared__ __align__(16) __hip_bfloat16 sA[2][TM * BK];
    __shared__ __align__(16) __hip_bfloat16 sB[2][TN * BK];
    __shared__ __align__(16) __hip_bfloat16 sH[2][(FUSE ? 16 : 1) * 64];  // halo rows

    // bank swizzle: BK=32 -> 4-chunk XOR over (row>>1); BK=64 -> 8-chunk over (row&7).
    auto SW = [](int row) { return (BK == 32) ? ((row >> 1) & 3) : (row & 7); };

    int bx = blockIdx.x, by = blockIdx.y;
    if ((gridDim.y & 7) == 0) {
        // R15 L2 super-tile decode (bijective for gx%8==0 or gx==1):
        const int bid = blockIdx.x + gridDim.x * blockIdx.y;
        const int xcd = bid & 7, s = bid >> 3;
        const int ypx = gridDim.y >> 3;                  // A-panels per XCD
        const int gx  = ((gridDim.x & 7) == 0) ? 8 : 1;  // bx-group width
        const int gsz = gx * ypx;                        // blocks per L2 group
        const int grp = s / gsz, r = s % gsz;
        bx = grp * gx + (r % gx);
        by = (r / gx) * 8 + xcd;
    }
    const int m0 = by * TM;
    const int n0 = bx * TN;
    const int k0 = blockIdx.z * Ksl;
    const int tid = threadIdx.x;
    const int w = tid >> 6, lane = tid & 63;
    const int wm = (w >> 1) * WM, wn = (w & 1) * WN;
    const int lrow = lane & 15, lq = lane >> 4;

    const int r0 = tid / C8;
    const int q = ((tid % C8) - SW(r0)) & (C8 - 1);
    const __hip_bfloat16* pa[PA];
    const __hip_bfloat16* pb[PB];
#pragma unroll
    for (int p = 0; p < PA; p++) pa[p] = A + (size_t)(m0 + r0 + RPP * p) * lda + k0 + q * 8;
#pragma unroll
    for (int p = 0; p < PB; p++) pb[p] = Bw + (size_t)(n0 + r0 + RPP * p) * ldb + k0 + q * 8;

    // halo staging (MODE 0, xproj half): rows m0-16..m0-1, 128 lanes x 16B.
    const bool isX = FUSE && (n0 < DIN);
    const __hip_bfloat16* ph = nullptr;
    if (FUSE) {
        const int rh = tid >> 3;
        const int qh = ((tid & 7) - (rh & 7)) & 7;
        ph = A + (size_t)(m0 - 16 + rh) * lda + k0 + qh * 8;
    }

    f32x4 acc[MT][NT];
#pragma unroll
    for (int i = 0; i < MT; i++)
#pragma unroll
        for (int j = 0; j < NT; j++) { acc[i][j][0]=0.f; acc[i][j][1]=0.f; acc[i][j][2]=0.f; acc[i][j][3]=0.f; }
    f32x4 hacc[FUSE ? NT : 1];
    if (FUSE)
#pragma unroll
        for (int j = 0; j < NT; j++) { hacc[j][0]=0.f; hacc[j][1]=0.f; hacc[j][2]=0.f; hacc[j][3]=0.f; }

    const int nk = Ksl / BK;
    // prologue: stage k-stage 0 into buffer 0
#pragma unroll
    for (int p = 0; p < PA; p++) glds16(pa[p], &sA[0][(tid + 256 * p) * 8]);
#pragma unroll
    for (int p = 0; p < PB; p++) glds16(pb[p], &sB[0][(tid + 256 * p) * 8]);
    if (isX && tid < 128) glds16(ph, &sH[0][tid * 8]);

    for (int kb = 0; kb < nk; ++kb) {
        const int cur = kb & 1, nxt = cur ^ 1;
        __syncthreads();   // drains DMAs for buf cur
        if (kb + 1 < nk) {
#pragma unroll
            for (int p = 0; p < PA; p++) { pa[p] += BK; glds16(pa[p], &sA[nxt][(tid + 256 * p) * 8]); }
#pragma unroll
            for (int p = 0; p < PB; p++) { pb[p] += BK; glds16(pb[p], &sB[nxt][(tid + 256 * p) * 8]); }
            if (isX && tid < 128) { ph += BK; glds16(ph, &sH[nxt][tid * 8]); }
        }
#pragma unroll
        for (int s = 0; s < BK / 32; s++) {   // K=32 halves per stage
            bf16x8 af[MT], bb[NT];
#pragma unroll
            for (int mt = 0; mt < MT; mt++) {
                const int row = wm + mt * 16 + lrow;
                const int pc = ((s * 4 + lq) + SW(row)) & (C8 - 1);
                af[mt] = *(const bf16x8*)&sA[cur][row * BK + pc * 8];
            }
#pragma unroll
            for (int nt = 0; nt < NT; nt++) {
                const int row = wn + nt * 16 + lrow;
                const int pc = ((s * 4 + lq) + SW(row)) & (C8 - 1);
                bb[nt] = *(const bf16x8*)&sB[cur][row * BK + pc * 8];
            }
#pragma unroll
            for (int mt = 0; mt < MT; mt++)
#pragma unroll
                for (int nt = 0; nt < NT; nt++)
                    acc[mt][nt] = __builtin_amdgcn_mfma_f32_16x16x32_bf16(af[mt], bb[nt], acc[mt][nt], 0, 0, 0);
            if (isX && w < 2) {   // halo tile on wm=0 waves (wave-uniform branch)
                const int pcH = ((s * 4 + lq) + (lrow & 7)) & 7;
                const bf16x8 afh = *(const bf16x8*)&sH[cur][lrow * 64 + pcH * 8];
#pragma unroll
                for (int nt = 0; nt < NT; nt++)
                    hacc[nt] = __builtin_amdgcn_mfma_f32_16x16x32_bf16(afh, bb[nt], hacc[nt], 0, 0, 0);
            }
        }
    }

    // ---------------- epilogue ----------------
    // C layout: row=(lane>>4)*4+r, col=lane&15 (m89/m91-verified)
    if constexpr (MODE == 0) {
        if (isX) {
            // fused conv+silu: stage [halo16 | main TM] x TN bf16 tile in LDS (reuse sB)
            __syncthreads();                       // all ds_reads of last stage done
            __hip_bfloat16* tile = (__hip_bfloat16*)&sB[0][0];
            constexpr int TS = TN + 8;             // 136: breaks 1KB bank alignment
#pragma unroll
            for (int mt = 0; mt < MT; mt++)
#pragma unroll
                for (int nt = 0; nt < NT; nt++) {
                    const int col = wn + nt * 16 + lrow;
#pragma unroll
                    for (int r = 0; r < 4; r++)
                        tile[(16 + wm + mt * 16 + lq * 4 + r) * TS + col] = __float2bfloat16(acc[mt][nt][r]);
                }
            if (w < 2) {
#pragma unroll
                for (int nt = 0; nt < NT; nt++) {
                    const int col = wn + nt * 16 + lrow;
#pragma unroll
                    for (int r = 0; r < 4; r++)
                        tile[(lq * 4 + r) * TS + col] = __float2bfloat16(hacc[nt][r]);
                }
            }
            __syncthreads();
            // conv(4)+silu: 2 cols x 16 rows per thread, rolling registers.
            // R18: post-conv values are ALSO written back into `tile` in place
            // (halo preloaded to regs + extra sync prevents the overwrite race).
            const int c2 = (tid & 63) * 2;
            const int rg = tid >> 6;               // 0..3
            const int dg = n0 + c2;
            const float4 wA = *(const float4*)&bias[dg * 4];
            const float4 wB = *(const float4*)&bias[dg * 4 + 4];
            const float cbA = bias2[dg], cbB = bias2[dg + 1];
            const int l0 = m0 & (LSEQ - 1);
            const int rbase = rg * 16;
            float a0, a1, a2, b0, b1, b2;
            if (l0 == 0 && rg == 0) {
                a0 = a1 = a2 = b0 = b1 = b2 = 0.f;
            } else {
                const int hr = 16 + rbase - 3;
                a0 = __bfloat162float(tile[(hr + 0) * TS + c2]);
                b0 = __bfloat162float(tile[(hr + 0) * TS + c2 + 1]);
                a1 = __bfloat162float(tile[(hr + 1) * TS + c2]);
                b1 = __bfloat162float(tile[(hr + 1) * TS + c2 + 1]);
                a2 = __bfloat162float(tile[(hr + 2) * TS + c2]);
                b2 = __bfloat162float(tile[(hr + 2) * TS + c2 + 1]);
            }
            __syncthreads();   // R18: all halo preloads done before overwrite
            __hip_bfloat16* xcbp = (__hip_bfloat16*)e0;
#pragma unroll 4
            for (int i = 0; i < 16; i++) {
                const int row = rbase + i;
                const float a3 = __bfloat162float(tile[(16 + row) * TS + c2]);
                const float b3 = __bfloat162float(tile[(16 + row) * TS + c2 + 1]);
                float sa = cbA + wA.x * a0 + wA.y * a1 + wA.z * a2 + wA.w * a3;
                float sb = cbB + wB.x * b0 + wB.y * b1 + wB.z * b2 + wB.w * b3;
                sa = sa / (1.f + __expf(-sa));
                sb = sb / (1.f + __expf(-sb));
                __hip_bfloat16 ha = __float2bfloat16(sa), hb = __float2bfloat16(sb);
                ushort2 o;
                o.x = (unsigned short)__hip_bfloat16_raw(ha).x;
                o.y = (unsigned short)__hip_bfloat16_raw(hb).x;
                *(ushort2*)&xcbp[(size_t)(m0 + row) * DIN + dg] = o;
                *(ushort2*)&tile[(16 + row) * TS + c2] = o;   // R18 in-place x_conv
                a0 = a1; a1 = a2; a2 = a3;
                b0 = b1; b1 = b2; b2 = b3;
            }
            // ---- R18: fused partial [dtin|Bm|Cm] projection (replaces gemm1) ----
            __syncthreads();   // post-conv tile complete
            {
                // wpb is allocated immediately after w1b (=Bw here); both 256B-mult.
                const __hip_bfloat16* wpb2 = Bw + (size_t)4096 * 1024;
                const int wm2 = (w >> 1) * 32, wn2 = (w & 1) * 48;
                f32x4 acc2[2][3];
#pragma unroll
                for (int mt2 = 0; mt2 < 2; mt2++)
#pragma unroll
                    for (int nt2 = 0; nt2 < 3; nt2++) {
                        acc2[mt2][nt2][0]=0.f; acc2[mt2][nt2][1]=0.f;
                        acc2[mt2][nt2][2]=0.f; acc2[mt2][nt2][3]=0.f;
                    }
#pragma unroll
                for (int ks = 0; ks < 4; ks++) {   // K=128 in 4 x K=32
                    bf16x8 af2[2], bb2[3];
#pragma unroll
                    for (int mt2 = 0; mt2 < 2; mt2++)
                        af2[mt2] = *(const bf16x8*)&tile[(16 + wm2 + mt2 * 16 + lrow) * TS + ks * 32 + lq * 8];
#pragma unroll
                    for (int nt2 = 0; nt2 < 3; nt2++)
                        bb2[nt2] = *(const bf16x8*)&wpb2[(size_t)(wn2 + nt2 * 16 + lrow) * 2048 + n0 + ks * 32 + lq * 8];
#pragma unroll
                    for (int mt2 = 0; mt2 < 2; mt2++)
#pragma unroll
                        for (int nt2 = 0; nt2 < 3; nt2++)
                            acc2[mt2][nt2] = __builtin_amdgcn_mfma_f32_16x16x32_bf16(af2[mt2], bb2[nt2], acc2[mt2][nt2], 0, 0, 0);
                }
#pragma unroll
                for (int mt2 = 0; mt2 < 2; mt2++)
#pragma unroll
                    for (int nt2 = 0; nt2 < 3; nt2++) {
                        const int gn = wn2 + nt2 * 16 + lrow;     // 0..95
                        const int gmb = m0 + wm2 + mt2 * 16 + lq * 4;
#pragma unroll
                        for (int r = 0; r < 4; r++) {
                            const int gm = gmb + r;
                            const float v = acc2[mt2][nt2][r];
                            if (gn < 64)      atomicAdd(Af + (size_t)gm * 64 + gn, v);
                            else if (gn < 80) atomicAdd(Af + 131072 + (size_t)gm * NST + (gn - 64), v);
                            else              atomicAdd(Af + 163840 + (size_t)gm * NST + (gn - 80), v);
                        }
                    }
            }
        } else {
            // z half: silu -> LDS tile -> coalesced 16B flush (R14)
            __syncthreads();
            __hip_bfloat16* tile = (__hip_bfloat16*)&sB[0][0];
            constexpr int TS = TN + 8;
#pragma unroll
            for (int mt = 0; mt < MT; mt++)
#pragma unroll
                for (int nt = 0; nt < NT; nt++) {
                    const int col = wn + nt * 16 + lrow;
#pragma unroll
                    for (int r = 0; r < 4; r++) {
                        const float v = acc[mt][nt][r];
                        const float sv = v / (1.f + __expf(-v));
                        tile[(wm + mt * 16 + lq * 4 + r) * TS + col] = __float2bfloat16(sv);
                    }
                }
            __syncthreads();
            const int rr = tid >> 4, cq = (tid & 15) * 8;
            __hip_bfloat16* gz = (__hip_bfloat16*)e1 + (size_t)m0 * DIN + (n0 - DIN);
#pragma unroll
            for (int p = 0; p < TM / 16; p++)
                *(bf16x8*)(gz + (size_t)(rr + 16 * p) * DIN + cq) =
                    *(const bf16x8*)&tile[(rr + 16 * p) * TS + cq];
        }
        return;
    }
    // generic epilogue: MODE 3 (out + residual) / MODE 4 (split-K atomic, R21)
#pragma unroll
    for (int mt = 0; mt < MT; mt++) {
#pragma unroll
        for (int nt = 0; nt < NT; nt++) {
            const int gn = n0 + wn + nt * 16 + lrow;
            if (gn >= N) continue;
            const int gmb = m0 + wm + mt * 16 + lq * 4;
#pragma unroll
            for (int r = 0; r < 4; r++) {
                const int gm = gmb + r;
                const float v = acc[mt][nt][r];
                if (MODE == 3)
                    ((float*)e0)[(size_t)gm * N + gn] = v + ((const float*)e1)[(size_t)gm * N + gn];
                else  // MODE 4: out pre-initialized with residual by prep
                    atomicAdd((float*)e0 + (size_t)gm * N + gn, v);
            }
        }
    }
}

// prep: weight f32->bf16 conversions + layernorm + zero(dtin|Bm|Cm)
// + R21: residual copy x -> out (split-K gemm3 atomicAdds on top).
#define NCVT 1654784   // 6,619,136 weight elems / 4
#define NZR  49152     // 196,608 floats / 4 (dtin|Bm|Cm zero)
#define NRES 524288    // 2048*1024 floats / 4 (residual copy)
__global__ void prep_kernel(const float* __restrict__ x, const float* __restrict__ ln_g,
                            const float* __restrict__ ln_b,
                            const float* __restrict__ w_in, const float* __restrict__ dtin_w,
                            const float* __restrict__ B_w, const float* __restrict__ C_w,
                            const float* __restrict__ dt_w, const float* __restrict__ out_w,
                            __hip_bfloat16* __restrict__ w1b, __hip_bfloat16* __restrict__ wpb,
                            __hip_bfloat16* __restrict__ dtwb, __hip_bfloat16* __restrict__ owb,
                            __hip_bfloat16* __restrict__ xn, float* __restrict__ zblock,
                            float* __restrict__ outp)
{
    const int b = blockIdx.x;
    const int tid = threadIdx.x;
    if (b < MR) {  // layernorm row b
        const float4 v = ((const float4*)(x + (size_t)b * DMOD))[tid];
        float s  = v.x + v.y + v.z + v.w;
        float sq = v.x * v.x + v.y * v.y + v.z * v.z + v.w * v.w;
#pragma unroll
        for (int off = 32; off >= 1; off >>= 1) {
            s  += __shfl_down(s, off, 64);
            sq += __shfl_down(sq, off, 64);
        }
        __shared__ float red[8];
        const int w = tid >> 6, lane = tid & 63;
        if (lane == 0) { red[w] = s; red[4 + w] = sq; }
        __syncthreads();
        s  = red[0] + red[1] + red[2] + red[3];
        sq = red[4] + red[5] + red[6] + red[7];
        const float mean = s * (1.f / DMOD);
        const float rstd = rsqrtf(sq * (1.f / DMOD) - mean * mean + 1e-5f);
        const int col = tid * 4;
        const float vv[4] = {v.x, v.y, v.z, v.w};
#pragma unroll
        for (int i = 0; i < 4; i++)
            xn[(size_t)b * DMOD + col + i] =
                __float2bfloat16((vv[i] - mean) * rstd * ln_g[col + i] + ln_b[col + i]);
        return;
    }
    const int nb = gridDim.x - MR;
    for (int v4 = (b - MR) * 256 + tid; v4 < NCVT + NZR + NRES; v4 += nb * 256) {
        if (v4 >= NCVT + NZR) {        // R21: residual copy
            const int j = v4 - (NCVT + NZR);
            ((float4*)outp)[j] = ((const float4*)x)[j];
            continue;
        }
        if (v4 >= NCVT) {
            float4 z; z.x = z.y = z.z = z.w = 0.f;
            ((float4*)zblock)[v4 - NCVT] = z;
            continue;
        }
        const int i = v4 * 4;
        const float* s; __hip_bfloat16* dk;
        if      (i < 4194304) { s = w_in   + i;             dk = w1b  + i; }
        else if (i < 4325376) { s = dtin_w + (i - 4194304); dk = wpb  + (i - 4194304); }
        else if (i < 4358144) { s = B_w    + (i - 4325376); dk = wpb  + 131072 + (i - 4325376); }
        else if (i < 4390912) { s = C_w    + (i - 4358144); dk = wpb  + 163840 + (i - 4358144); }
        else if (i < 4521984) { s = dt_w   + (i - 4390912); dk = dtwb + (i - 4390912); }
        else                  { s = out_w  + (i - 4521984); dk = owb  + (i - 4521984); }
        const float4 f = *(const float4*)s;
        ushort4 o;
        o.x = (unsigned short)(__hip_bfloat16_raw(__float2bfloat16(f.x)).x);
        o.y = (unsigned short)(__hip_bfloat16_raw(__float2bfloat16(f.y)).x);
        o.z = (unsigned short)(__hip_bfloat16_raw(__float2bfloat16(f.z)).x);
        o.w = (unsigned short)(__hip_bfloat16_raw(__float2bfloat16(f.w)).x);
        *(ushort4*)dk = o;
    }
}

// ===================== chunked selective scan =====================
// R20: block = 64 d-cols x 4 nh (4 states/thread), 2048 blocks (8/CU), 20KB LDS.
// blk = bb*1024 + c*32 + dtile; d0 = dtile*64.
// p1 computes dt in an MFMA preamble (R19 numerics) -> sDT + coalesced dtb flush.

__global__ __launch_bounds__(256) void scan_p1(
    const float* __restrict__ fdtin, const float* __restrict__ dtin_b,
    const __hip_bfloat16* __restrict__ dtwb, const float* __restrict__ dt_b,
    const __hip_bfloat16* __restrict__ u,
    const float* __restrict__ Bm, const float* __restrict__ A_log,
    float* __restrict__ Aprod, float* __restrict__ Bacc,
    __hip_bfloat16* __restrict__ dtb)
{
    __shared__ float sB[TCH * NST];
    __shared__ __align__(16) __hip_bfloat16 sDT[TCH * 64];
    __shared__ __align__(16) __hip_bfloat16 sU [TCH * 64];
    const int blk = blockIdx.x;
    const int bb = blk >> 10, c = (blk >> 5) & 31, dtile = blk & 31;
    const int tid = threadIdx.x;
    const int nh = tid & 3, dl = tid >> 2;     // dl 0..63
    const int d = dtile * 64 + dl;
    const int d0 = dtile * 64;
    const int row0 = bb * LSEQ + c * TCH;
    const int wv = tid >> 6, lane = tid & 63;
    const int lrow = lane & 15, lq = lane >> 4;

    {   // DMA-stage u tile: 32 rows x 64 cols (128B/row), one pass
        const int r = tid >> 3, cq = (tid & 7) * 8;
        const __hip_bfloat16* gu = u + (size_t)row0 * DIN + d0;
        glds16(gu + (size_t)r * DIN + cq, &sU[r * 64 + cq]);
    }
    sB[tid]       = Bm[(size_t)row0 * NST + tid];
    sB[tid + 256] = Bm[(size_t)row0 * NST + tid + 256];

    // ---- dt preamble (R19/R20): 32t x 64d tile, wave wv -> mt=wv>>1, nt pair
    {
        const int mt = wv >> 1;
        const int ng = (wv & 1) * 2;
        f32x4 dacc[2];
#pragma unroll
        for (int nt = 0; nt < 2; nt++) { dacc[nt][0]=0.f; dacc[nt][1]=0.f; dacc[nt][2]=0.f; dacc[nt][3]=0.f; }
#pragma unroll
        for (int s = 0; s < 2; s++) {   // K=64 in 2 x K=32
            const float* ap = fdtin + (size_t)(row0 + mt * 16 + lrow) * 64 + s * 32 + lq * 8;
            const float4 f0 = *(const float4*)ap;
            const float4 f1 = *(const float4*)(ap + 4);
            const float4 b0 = *(const float4*)&dtin_b[s * 32 + lq * 8];
            const float4 b1 = *(const float4*)&dtin_b[s * 32 + lq * 8 + 4];
            bf16x8 afr;
            afr[0] = f2b(f0.x + b0.x); afr[1] = f2b(f0.y + b0.y);
            afr[2] = f2b(f0.z + b0.z); afr[3] = f2b(f0.w + b0.w);
            afr[4] = f2b(f1.x + b1.x); afr[5] = f2b(f1.y + b1.y);
            afr[6] = f2b(f1.z + b1.z); afr[7] = f2b(f1.w + b1.w);
#pragma unroll
            for (int nt = 0; nt < 2; nt++) {
                const bf16x8 bfr = *(const bf16x8*)&dtwb[(size_t)(d0 + (ng + nt) * 16 + lrow) * 64 + s * 32 + lq * 8];
                dacc[nt] = __builtin_amdgcn_mfma_f32_16x16x32_bf16(afr, bfr, dacc[nt], 0, 0, 0);
            }
        }
        // C layout: row=lq*4+r, col=lrow -> t = mt*16+lq*4+r, dloc = (ng+nt)*16+lrow
#pragma unroll
        for (int nt = 0; nt < 2; nt++) {
            const int dloc = (ng + nt) * 16 + lrow;
            const float db = dt_b[d0 + dloc];
#pragma unroll
            for (int r = 0; r < 4; r++) {
                const float xx = dacc[nt][r] + db;
                const float sp = (xx > 20.f) ? xx : log1pf(__expf(xx));
                sDT[(mt * 16 + lq * 4 + r) * 64 + dloc] = __float2bfloat16(sp);
            }
        }
    }

    float a2[4];
    {
        const float4 al = *(const float4*)&A_log[(size_t)d * NST + nh * 4];
        a2[0] = -__expf(al.x) * LOG2E; a2[1] = -__expf(al.y) * LOG2E;
        a2[2] = -__expf(al.z) * LOG2E; a2[3] = -__expf(al.w) * LOG2E;
    }
    __syncthreads();   // drains glds16 DMA + sB/sDT stores

    {   // coalesced dtb flush for p3: one 16B pass
        const int r = tid >> 3, cq = (tid & 7) * 8;
        __hip_bfloat16* gdt = dtb + (size_t)row0 * DIN + d0;
        *(bf16x8*)(gdt + (size_t)r * DIN + cq) = *(const bf16x8*)&sDT[r * 64 + cq];
    }

    float h[4], Ap[4];
#pragma unroll
    for (int j = 0; j < 4; j++) { h[j] = 0.f; Ap[j] = 1.f; }

#pragma unroll 4
    for (int t = 0; t < TCH; t++) {
        const float dtv = __bfloat162float(sDT[t * 64 + dl]);
        const float uv  = __bfloat162float(sU [t * 64 + dl]);
        const float du = dtv * uv;
        float bv[4];
        *(float4*)&bv[0] = *(const float4*)&sB[t * NST + nh * 4];
#pragma unroll
        for (int j = 0; j < 4; j++) {
            const float e = EXP2F(dtv * a2[j]);
            Ap[j] *= e;
            h[j] = h[j] * e + du * bv[j];
        }
    }
    const size_t idx = (((size_t)bb * CCH + c) * DIN + d) * NST + nh * 4;
    *(float4*)&Aprod[idx] = make_float4(Ap[0], Ap[1], Ap[2], Ap[3]);
    *(float4*)&Bacc[idx]  = make_float4(h[0], h[1], h[2], h[3]);
}

// p2: inter-chunk serial chain. Prefetch ALL (Aprod,Bacc) pairs into registers
// (independent loads, one latency), then the CCH-long FMA chain + stores.
__global__ __launch_bounds__(256) void scan_p2(
    const float* __restrict__ Aprod, const float* __restrict__ Bacc,
    float* __restrict__ hstart)
{
    const int i = blockIdx.x * 256 + threadIdx.x;
    const int bb = i >> 15;          // DIN*NST = 32768 per batch
    const int dn = i & 32767;
    const size_t base = (((size_t)bb * CCH) << 15) + dn;
    float ap[CCH], bc[CCH];
#pragma unroll
    for (int c = 0; c < CCH; c++) {
        ap[c] = Aprod[base + ((size_t)c << 15)];
        bc[c] = Bacc[base + ((size_t)c << 15)];
    }
    float hs = 0.f;
#pragma unroll
    for (int c = 0; c < CCH; c++) {
        hstart[base + ((size_t)c << 15)] = hs;
        hs = fmaf(ap[c], hs, bc[c]);
    }
}

__global__ __launch_bounds__(256) void scan_p3(
    const __hip_bfloat16* __restrict__ dt, const __hip_bfloat16* __restrict__ u,
    const float* __restrict__ Bm, const float* __restrict__ Cm,
    const float* __restrict__ A_log, const float* __restrict__ Dp,
    const __hip_bfloat16* __restrict__ zs, const float* __restrict__ hstart,
    __hip_bfloat16* __restrict__ y)
{
    __shared__ float sB[TCH * NST], sC[TCH * NST];
    __shared__ __align__(16) __hip_bfloat16 sDT[TCH * 64];
    __shared__ __align__(16) __hip_bfloat16 sU [TCH * 64];
    __shared__ __align__(16) __hip_bfloat16 sZ [TCH * 64];
    __shared__ __align__(16) __hip_bfloat16 sY [TCH * 64];
    const int blk = blockIdx.x;
    const int bb = blk >> 10, c = (blk >> 5) & 31, dtile = blk & 31;
    const int tid = threadIdx.x;
    const int nh = tid & 3, dl = tid >> 2;     // dl 0..63
    const int d = dtile * 64 + dl;
    const int d0 = dtile * 64;
    const int row0 = bb * LSEQ + c * TCH;

    {   // DMA-stage dt/u/z tiles: 32 rows x 64 cols, one pass each
        const int r = tid >> 3, cq = (tid & 7) * 8;
        const __hip_bfloat16* gdt = dt + (size_t)row0 * DIN + d0;
        const __hip_bfloat16* gu  = u  + (size_t)row0 * DIN + d0;
        const __hip_bfloat16* gz  = zs + (size_t)row0 * DIN + d0;
        glds16(gdt + (size_t)r * DIN + cq, &sDT[r * 64 + cq]);
        glds16(gu  + (size_t)r * DIN + cq, &sU [r * 64 + cq]);
        glds16(gz  + (size_t)r * DIN + cq, &sZ [r * 64 + cq]);
    }
    sB[tid]       = Bm[(size_t)row0 * NST + tid];
    sB[tid + 256] = Bm[(size_t)row0 * NST + tid + 256];
    sC[tid]       = Cm[(size_t)row0 * NST + tid];
    sC[tid + 256] = Cm[(size_t)row0 * NST + tid + 256];

    float a2[4];
    {
        const float4 al = *(const float4*)&A_log[(size_t)d * NST + nh * 4];
        a2[0] = -__expf(al.x) * LOG2E; a2[1] = -__expf(al.y) * LOG2E;
        a2[2] = -__expf(al.z) * LOG2E; a2[3] = -__expf(al.w) * LOG2E;
    }
    const float Dd = Dp[d];
    const size_t idx = (((size_t)bb * CCH + c) * DIN + d) * NST + nh * 4;
    float h[4];
    *(float4*)&h[0] = *(const float4*)&hstart[idx];
    __syncthreads();   // drains glds16 DMAs + sB/sC stores

#pragma unroll 4
    for (int t = 0; t < TCH; t++) {
        const float dtv = __bfloat162float(sDT[t * 64 + dl]);
        const float uv  = __bfloat162float(sU [t * 64 + dl]);
        const float du = dtv * uv;
        float bv[4], cv[4];
        *(float4*)&bv[0] = *(const float4*)&sB[t * NST + nh * 4];
        *(float4*)&cv[0] = *(const float4*)&sC[t * NST + nh * 4];
        float yp = 0.f;
#pragma unroll
        for (int j = 0; j < 4; j++) {
            const float e = EXP2F(dtv * a2[j]);
            h[j] = h[j] * e + du * bv[j];
            yp += h[j] * cv[j];
        }
        yp += __shfl_xor(yp, 1, 64);
        yp += __shfl_xor(yp, 2, 64);
        if (nh == 0) {
            const float zv = __bfloat162float(sZ[t * 64 + dl]);
            sY[t * 64 + dl] = __float2bfloat16((yp + uv * Dd) * zv);
        }
    }
    __syncthreads();
    {   // coalesced y flush: one 16B pass
        const int r = tid >> 3, cq = (tid & 7) * 8;
        __hip_bfloat16* gy = y + (size_t)row0 * DIN + d0;
        *(bf16x8*)(gy + (size_t)r * DIN + cq) = *(const bf16x8*)&sY[r * 64 + cq];
    }
}

extern "C" void kernel_launch(void* const* d_in, const int* in_sizes, int n_in,
                              void* d_out, int out_size, void* d_ws, size_t ws_size,
                              hipStream_t stream) {
    const float* x      = (const float*)d_in[0];
    const float* ln_g   = (const float*)d_in[1];
    const float* ln_b   = (const float*)d_in[2];
    const float* w_in   = (const float*)d_in[3];   // (4096,1024)
    const float* conv_w = (const float*)d_in[4];   // (2048,1,4)
    const float* conv_b = (const float*)d_in[5];
    const float* dtin_w = (const float*)d_in[6];   // (64,2048)
    const float* dtin_b = (const float*)d_in[7];
    const float* dt_w   = (const float*)d_in[8];   // (2048,64)
    const float* dt_b   = (const float*)d_in[9];
    const float* B_w    = (const float*)d_in[10];  // (16,2048)
    const float* C_w    = (const float*)d_in[11];
    const float* A_log  = (const float*)d_in[12];  // (2048,16)
    const float* Dp     = (const float*)d_in[13];
    const float* out_w  = (const float*)d_in[14];  // (1024,2048)
    float* out = (float*)d_out;

    char* ws = (char*)d_ws;
    auto alloc = [&](size_t bytes) { char* p = ws; ws += (bytes + 255) & ~255ull; return p; };
    __hip_bfloat16* w1b   = (__hip_bfloat16*)alloc((size_t)4096 * 1024 * 2);   // R18: wpb MUST
    __hip_bfloat16* wpb   = (__hip_bfloat16*)alloc((size_t)96 * 2048 * 2);     // follow w1b
    __hip_bfloat16* dtwb  = (__hip_bfloat16*)alloc((size_t)2048 * 64 * 2);
    __hip_bfloat16* owb   = (__hip_bfloat16*)alloc((size_t)1024 * 2048 * 2);
    __hip_bfloat16* xnb   = (__hip_bfloat16*)alloc((size_t)MR * DMOD * 2);
    __hip_bfloat16* zs    = (__hip_bfloat16*)alloc((size_t)MR * DIN * 2);
    __hip_bfloat16* xcb   = (__hip_bfloat16*)alloc((size_t)MR * DIN * 2);
    __hip_bfloat16* dtb   = (__hip_bfloat16*)alloc((size_t)MR * DIN * 2);
    __hip_bfloat16* yb    = (__hip_bfloat16*)alloc((size_t)MR * DIN * 2);
    float*          zblock= (float*)alloc((size_t)196608 * 4);    // dtin|Bm|Cm (zeroed by prep)
    float*          Aprod = (float*)alloc((size_t)BL * CCH * DIN * NST * 4);
    float*          Bacc  = (float*)alloc((size_t)BL * CCH * DIN * NST * 4);
    float*          hstart= (float*)alloc((size_t)BL * CCH * DIN * NST * 4);

    float* fdtin = zblock;            // 2048 x 64
    float* Bmf   = zblock + 131072;   // 2048 x 16 ; Cmf = Bmf + 32768 (contiguous)
    float* Cmf   = Bmf + (size_t)MR * NST;

    // 1. prep: weight conversions + layernorm + zero accum + residual copy (R21)
    prep_kernel<<<MR + 896, 256, 0, stream>>>(x, ln_g, ln_b, w_in, dtin_w, B_w, C_w, dt_w,
                                              out_w, w1b, wpb, dtwb, owb, xnb, zblock, out);

    // 2. in_proj + fused conv+silu + fused [dtin|Bm|Cm] projection (R18):
    //    (2048 x 4096), K=1024 — 1024 blocks; zblock passed via Af.
    gemm_bt<0, 64, 128, 64><<<dim3(32, 32, 1), 256, 0, stream>>>(
        xnb, 1024, w1b, 1024, MR, 4096, 1024, xcb, zs, conv_w, conv_b, zblock);

    // 3-5. chunked selective scan (R20: 2048 blocks, 4 states/thread)
    scan_p1<<<BL * CCH * 32, 256, 0, stream>>>(fdtin, dtin_b, dtwb, dt_b,
                                               xcb, Bmf, A_log, Aprod, Bacc, dtb);
    scan_p2<<<BL * DIN * NST / 256, 256, 0, stream>>>(Aprod, Bacc, hstart);
    scan_p3<<<BL * CCH * 32, 256, 0, stream>>>(dtb, xcb, Bmf, Cmf,
                                               A_log, Dp, zs, hstart, yb);

    // 6. out += y @ out_w^T : (2048 x 1024), K=2048, split-K=2, TN=128 (R21)
    //    — 512 blocks, residual pre-initialized by prep.
    gemm_bt<4, 64, 128, 64><<<dim3(8, 32, 2), 256, 0, stream>>>(
        yb, 2048, owb, 2048, MR, DMOD, 1024, out, nullptr, nullptr, nullptr, nullptr);
}

// Round 14
// 211.039 us; speedup vs baseline: 1.0460x; 1.0460x over previous
//
#include <hip/hip_runtime.h>
#include <hip/hip_bf16.h>
#include <cstdint>

// ---- problem constants ----
#define BL    2
#define LSEQ  1024
#define DMOD  1024
#define DIN   2048      // inner dim
#define NST   16        // d_state
#define DTRK  64        // dt rank
#define MR    (BL*LSEQ) // 2048 rows

// chunked scan: C chunks of T timesteps
// R13: scan is LATENCY-bound; u/z staged via glds16 so the serial t-chain is
// LDS+VALU only. R17: NEVER grid.sync (~250us/sync). R19: dt proj fused into
// p1 preamble. R20: 4 states/thread, 64 d-cols/block -> 2048 blocks (8/CU),
// half the per-t chain (221.6 -> 213.7).
// R21 REVERTED: split-K atomicAdd out-proj cost +23us (scattered 4B atomics).
// R22: gemm3 BK=128 — K-steps 32->16, 2 blocks/CU: per-CU serialized
// barrier-drains 96 -> 32 (gemm3's epilogue is trivial, unlike R9's case).
#define CCH 32
#define TCH 32          // LSEQ / CCH

typedef __bf16 bf16x8 __attribute__((ext_vector_type(8)));
typedef float  f32x4  __attribute__((ext_vector_type(4)));

#if __has_builtin(__builtin_amdgcn_exp2f)
#define EXP2F(x) __builtin_amdgcn_exp2f(x)
#else
#define EXP2F(x) exp2f(x)
#endif
#define LOG2E 1.4426950408889634f

// async global->LDS, 16B per lane. LDS dest = wave-uniform base + lane*16 (m104).
__device__ __forceinline__ void glds16(const void* g, const void* l) {
    __builtin_amdgcn_global_load_lds(
        (__attribute__((address_space(1))) void*)(uintptr_t)(g),
        (__attribute__((address_space(3))) void*)(uint32_t)(uintptr_t)(l),
        16, 0, 0);
}

__device__ __forceinline__ __bf16 f2b(float f) {
    __hip_bfloat16 t = __float2bfloat16(f);
    return *(__bf16*)&t;
}

// C[M][N] = A[M][K] (bf16,lda) * B[N][K]^T (bf16,ldb), fp32 accum.
// R9: 64x128/BK=64 at 3-4 blocks/CU is the local optimum for gemm0.
// R10 profile: gemm0 = 43us, MfmaUtil 17%, nothing saturated -> structural.
// R14/R15: LDS-coalesced epilogues + L2 super-tile decode (neutral, kept).
// R18: gemm1 ([dtin|Bm|Cm] proj) FUSED into MODE 0 isX epilogue.
// MODE 0 (in_proj): xproj half: conv+silu -> e0=xcb + fused proj; z half ->
//   silu -> e1=zs (LDS-coalesced).
// MODE 3: e0=float* out = acc + e1[gm*N+gn] (residual)      [out proj]
template <int MODE, int TM, int TN, int BK>
__global__ __launch_bounds__(256, 3) void gemm_bt(
    const __hip_bfloat16* __restrict__ A, int lda,
    const __hip_bfloat16* __restrict__ Bw, int ldb,
    int M, int N, int Ksl,
    void* __restrict__ e0, void* __restrict__ e1,
    const float* __restrict__ bias, const float* __restrict__ bias2,
    float* __restrict__ Af)
{
    constexpr bool FUSE = (MODE == 0);
    static_assert(!FUSE || BK == 64, "fused conv epilogue assumes BK=64");
    static_assert((MODE != 0) || TN == 128, "LDS flush assumes TN=128");
    constexpr int WM = TM / 2, WN = TN / 2;
    constexpr int MT = WM / 16, NT = WN / 16;
    constexpr int C8 = BK / 8;          // 16B chunks per row
    constexpr int RPP = 256 / C8;       // rows staged per 4KB DMA pass
    constexpr int PA = TM / RPP, PB = TN / RPP;
    __shared__ __align__(16) __hip_bfloat16 sA[2][TM * BK];
    __shared__ __align__(16) __hip_bfloat16 sB[2][TN * BK];
    __shared__ __align__(16) __hip_bfloat16 sH[2][(FUSE ? 16 : 1) * 64];  // halo rows

    // bank swizzle: BK=32 -> 4-chunk XOR over (row>>1); else C8-chunk over (row&7).
    auto SW = [](int row) { return (BK == 32) ? ((row >> 1) & 3) : (row & 7); };

    int bx = blockIdx.x, by = blockIdx.y;
    if ((gridDim.y & 7) == 0) {
        // R15 L2 super-tile decode (bijective for gx%8==0 or gx==1):
        const int bid = blockIdx.x + gridDim.x * blockIdx.y;
        const int xcd = bid & 7, s = bid >> 3;
        const int ypx = gridDim.y >> 3;                  // A-panels per XCD
        const int gx  = ((gridDim.x & 7) == 0) ? 8 : 1;  // bx-group width
        const int gsz = gx * ypx;                        // blocks per L2 group
        const int grp = s / gsz, r = s % gsz;
        bx = grp * gx + (r % gx);
        by = (r / gx) * 8 + xcd;
    }
    const int m0 = by * TM;
    const int n0 = bx * TN;
    const int k0 = blockIdx.z * Ksl;
    const int tid = threadIdx.x;
    const int w = tid >> 6, lane = tid & 63;
    const int wm = (w >> 1) * WM, wn = (w & 1) * WN;
    const int lrow = lane & 15, lq = lane >> 4;

    const int r0 = tid / C8;
    const int q = ((tid % C8) - SW(r0)) & (C8 - 1);
    const __hip_bfloat16* pa[PA];
    const __hip_bfloat16* pb[PB];
#pragma unroll
    for (int p = 0; p < PA; p++) pa[p] = A + (size_t)(m0 + r0 + RPP * p) * lda + k0 + q * 8;
#pragma unroll
    for (int p = 0; p < PB; p++) pb[p] = Bw + (size_t)(n0 + r0 + RPP * p) * ldb + k0 + q * 8;

    // halo staging (MODE 0, xproj half): rows m0-16..m0-1, 128 lanes x 16B.
    const bool isX = FUSE && (n0 < DIN);
    const __hip_bfloat16* ph = nullptr;
    if (FUSE) {
        const int rh = tid >> 3;
        const int qh = ((tid & 7) - (rh & 7)) & 7;
        ph = A + (size_t)(m0 - 16 + rh) * lda + k0 + qh * 8;
    }

    f32x4 acc[MT][NT];
#pragma unroll
    for (int i = 0; i < MT; i++)
#pragma unroll
        for (int j = 0; j < NT; j++) { acc[i][j][0]=0.f; acc[i][j][1]=0.f; acc[i][j][2]=0.f; acc[i][j][3]=0.f; }
    f32x4 hacc[FUSE ? NT : 1];
    if (FUSE)
#pragma unroll
        for (int j = 0; j < NT; j++) { hacc[j][0]=0.f; hacc[j][1]=0.f; hacc[j][2]=0.f; hacc[j][3]=0.f; }

    const int nk = Ksl / BK;
    // prologue: stage k-stage 0 into buffer 0
#pragma unroll
    for (int p = 0; p < PA; p++) glds16(pa[p], &sA[0][(tid + 256 * p) * 8]);
#pragma unroll
    for (int p = 0; p < PB; p++) glds16(pb[p], &sB[0][(tid + 256 * p) * 8]);
    if (isX && tid < 128) glds16(ph, &sH[0][tid * 8]);

    for (int kb = 0; kb < nk; ++kb) {
        const int cur = kb & 1, nxt = cur ^ 1;
        __syncthreads();   // drains DMAs for buf cur
        if (kb + 1 < nk) {
#pragma unroll
            for (int p = 0; p < PA; p++) { pa[p] += BK; glds16(pa[p], &sA[nxt][(tid + 256 * p) * 8]); }
#pragma unroll
            for (int p = 0; p < PB; p++) { pb[p] += BK; glds16(pb[p], &sB[nxt][(tid + 256 * p) * 8]); }
            if (isX && tid < 128) { ph += BK; glds16(ph, &sH[nxt][tid * 8]); }
        }
#pragma unroll
        for (int s = 0; s < BK / 32; s++) {   // K=32 halves per stage
            bf16x8 af[MT], bb[NT];
#pragma unroll
            for (int mt = 0; mt < MT; mt++) {
                const int row = wm + mt * 16 + lrow;
                const int pc = ((s * 4 + lq) + SW(row)) & (C8 - 1);
                af[mt] = *(const bf16x8*)&sA[cur][row * BK + pc * 8];
            }
#pragma unroll
            for (int nt = 0; nt < NT; nt++) {
                const int row = wn + nt * 16 + lrow;
                const int pc = ((s * 4 + lq) + SW(row)) & (C8 - 1);
                bb[nt] = *(const bf16x8*)&sB[cur][row * BK + pc * 8];
            }
#pragma unroll
            for (int mt = 0; mt < MT; mt++)
#pragma unroll
                for (int nt = 0; nt < NT; nt++)
                    acc[mt][nt] = __builtin_amdgcn_mfma_f32_16x16x32_bf16(af[mt], bb[nt], acc[mt][nt], 0, 0, 0);
            if (isX && w < 2) {   // halo tile on wm=0 waves (wave-uniform branch)
                const int pcH = ((s * 4 + lq) + (lrow & 7)) & 7;
                const bf16x8 afh = *(const bf16x8*)&sH[cur][lrow * 64 + pcH * 8];
#pragma unroll
                for (int nt = 0; nt < NT; nt++)
                    hacc[nt] = __builtin_amdgcn_mfma_f32_16x16x32_bf16(afh, bb[nt], hacc[nt], 0, 0, 0);
            }
        }
    }

    // ---------------- epilogue ----------------
    // C layout: row=(lane>>4)*4+r, col=lane&15 (m89/m91-verified)
    if constexpr (MODE == 0) {
        if (isX) {
            // fused conv+silu: stage [halo16 | main TM] x TN bf16 tile in LDS (reuse sB)
            __syncthreads();                       // all ds_reads of last stage done
            __hip_bfloat16* tile = (__hip_bfloat16*)&sB[0][0];
            constexpr int TS = TN + 8;             // 136: breaks 1KB bank alignment
#pragma unroll
            for (int mt = 0; mt < MT; mt++)
#pragma unroll
                for (int nt = 0; nt < NT; nt++) {
                    const int col = wn + nt * 16 + lrow;
#pragma unroll
                    for (int r = 0; r < 4; r++)
                        tile[(16 + wm + mt * 16 + lq * 4 + r) * TS + col] = __float2bfloat16(acc[mt][nt][r]);
                }
            if (w < 2) {
#pragma unroll
                for (int nt = 0; nt < NT; nt++) {
                    const int col = wn + nt * 16 + lrow;
#pragma unroll
                    for (int r = 0; r < 4; r++)
                        tile[(lq * 4 + r) * TS + col] = __float2bfloat16(hacc[nt][r]);
                }
            }
            __syncthreads();
            // conv(4)+silu: 2 cols x 16 rows per thread, rolling registers.
            // R18: post-conv values are ALSO written back into `tile` in place
            // (halo preloaded to regs + extra sync prevents the overwrite race).
            const int c2 = (tid & 63) * 2;
            const int rg = tid >> 6;               // 0..3
            const int dg = n0 + c2;
            const float4 wA = *(const float4*)&bias[dg * 4];
            const float4 wB = *(const float4*)&bias[dg * 4 + 4];
            const float cbA = bias2[dg], cbB = bias2[dg + 1];
            const int l0 = m0 & (LSEQ - 1);
            const int rbase = rg * 16;
            float a0, a1, a2, b0, b1, b2;
            if (l0 == 0 && rg == 0) {
                a0 = a1 = a2 = b0 = b1 = b2 = 0.f;
            } else {
                const int hr = 16 + rbase - 3;
                a0 = __bfloat162float(tile[(hr + 0) * TS + c2]);
                b0 = __bfloat162float(tile[(hr + 0) * TS + c2 + 1]);
                a1 = __bfloat162float(tile[(hr + 1) * TS + c2]);
                b1 = __bfloat162float(tile[(hr + 1) * TS + c2 + 1]);
                a2 = __bfloat162float(tile[(hr + 2) * TS + c2]);
                b2 = __bfloat162float(tile[(hr + 2) * TS + c2 + 1]);
            }
            __syncthreads();   // R18: all halo preloads done before overwrite
            __hip_bfloat16* xcbp = (__hip_bfloat16*)e0;
#pragma unroll 4
            for (int i = 0; i < 16; i++) {
                const int row = rbase + i;
                const float a3 = __bfloat162float(tile[(16 + row) * TS + c2]);
                const float b3 = __bfloat162float(tile[(16 + row) * TS + c2 + 1]);
                float sa = cbA + wA.x * a0 + wA.y * a1 + wA.z * a2 + wA.w * a3;
                float sb = cbB + wB.x * b0 + wB.y * b1 + wB.z * b2 + wB.w * b3;
                sa = sa / (1.f + __expf(-sa));
                sb = sb / (1.f + __expf(-sb));
                __hip_bfloat16 ha = __float2bfloat16(sa), hb = __float2bfloat16(sb);
                ushort2 o;
                o.x = (unsigned short)__hip_bfloat16_raw(ha).x;
                o.y = (unsigned short)__hip_bfloat16_raw(hb).x;
                *(ushort2*)&xcbp[(size_t)(m0 + row) * DIN + dg] = o;
                *(ushort2*)&tile[(16 + row) * TS + c2] = o;   // R18 in-place x_conv
                a0 = a1; a1 = a2; a2 = a3;
                b0 = b1; b1 = b2; b2 = b3;
            }
            // ---- R18: fused partial [dtin|Bm|Cm] projection (replaces gemm1) ----
            __syncthreads();   // post-conv tile complete
            {
                // wpb is allocated immediately after w1b (=Bw here); both 256B-mult.
                const __hip_bfloat16* wpb2 = Bw + (size_t)4096 * 1024;
                const int wm2 = (w >> 1) * 32, wn2 = (w & 1) * 48;
                f32x4 acc2[2][3];
#pragma unroll
                for (int mt2 = 0; mt2 < 2; mt2++)
#pragma unroll
                    for (int nt2 = 0; nt2 < 3; nt2++) {
                        acc2[mt2][nt2][0]=0.f; acc2[mt2][nt2][1]=0.f;
                        acc2[mt2][nt2][2]=0.f; acc2[mt2][nt2][3]=0.f;
                    }
#pragma unroll
                for (int ks = 0; ks < 4; ks++) {   // K=128 in 4 x K=32
                    bf16x8 af2[2], bb2[3];
#pragma unroll
                    for (int mt2 = 0; mt2 < 2; mt2++)
                        af2[mt2] = *(const bf16x8*)&tile[(16 + wm2 + mt2 * 16 + lrow) * TS + ks * 32 + lq * 8];
#pragma unroll
                    for (int nt2 = 0; nt2 < 3; nt2++)
                        bb2[nt2] = *(const bf16x8*)&wpb2[(size_t)(wn2 + nt2 * 16 + lrow) * 2048 + n0 + ks * 32 + lq * 8];
#pragma unroll
                    for (int mt2 = 0; mt2 < 2; mt2++)
#pragma unroll
                        for (int nt2 = 0; nt2 < 3; nt2++)
                            acc2[mt2][nt2] = __builtin_amdgcn_mfma_f32_16x16x32_bf16(af2[mt2], bb2[nt2], acc2[mt2][nt2], 0, 0, 0);
                }
#pragma unroll
                for (int mt2 = 0; mt2 < 2; mt2++)
#pragma unroll
                    for (int nt2 = 0; nt2 < 3; nt2++) {
                        const int gn = wn2 + nt2 * 16 + lrow;     // 0..95
                        const int gmb = m0 + wm2 + mt2 * 16 + lq * 4;
#pragma unroll
                        for (int r = 0; r < 4; r++) {
                            const int gm = gmb + r;
                            const float v = acc2[mt2][nt2][r];
                            if (gn < 64)      atomicAdd(Af + (size_t)gm * 64 + gn, v);
                            else if (gn < 80) atomicAdd(Af + 131072 + (size_t)gm * NST + (gn - 64), v);
                            else              atomicAdd(Af + 163840 + (size_t)gm * NST + (gn - 80), v);
                        }
                    }
            }
        } else {
            // z half: silu -> LDS tile -> coalesced 16B flush (R14)
            __syncthreads();
            __hip_bfloat16* tile = (__hip_bfloat16*)&sB[0][0];
            constexpr int TS = TN + 8;
#pragma unroll
            for (int mt = 0; mt < MT; mt++)
#pragma unroll
                for (int nt = 0; nt < NT; nt++) {
                    const int col = wn + nt * 16 + lrow;
#pragma unroll
                    for (int r = 0; r < 4; r++) {
                        const float v = acc[mt][nt][r];
                        const float sv = v / (1.f + __expf(-v));
                        tile[(wm + mt * 16 + lq * 4 + r) * TS + col] = __float2bfloat16(sv);
                    }
                }
            __syncthreads();
            const int rr = tid >> 4, cq = (tid & 15) * 8;
            __hip_bfloat16* gz = (__hip_bfloat16*)e1 + (size_t)m0 * DIN + (n0 - DIN);
#pragma unroll
            for (int p = 0; p < TM / 16; p++)
                *(bf16x8*)(gz + (size_t)(rr + 16 * p) * DIN + cq) =
                    *(const bf16x8*)&tile[(rr + 16 * p) * TS + cq];
        }
        return;
    }
    // generic epilogue: MODE 3 (out + residual)
#pragma unroll
    for (int mt = 0; mt < MT; mt++) {
#pragma unroll
        for (int nt = 0; nt < NT; nt++) {
            const int gn = n0 + wn + nt * 16 + lrow;
            if (gn >= N) continue;
            const int gmb = m0 + wm + mt * 16 + lq * 4;
#pragma unroll
            for (int r = 0; r < 4; r++) {
                const int gm = gmb + r;
                ((float*)e0)[(size_t)gm * N + gn] = acc[mt][nt][r] + ((const float*)e1)[(size_t)gm * N + gn];
            }
        }
    }
}

// prep: weight f32->bf16 conversions + layernorm + zero(dtin|Bm|Cm), one dispatch.
#define NCVT 1654784   // 6,619,136 weight elems / 4
#define NZR  49152     // 196,608 floats / 4 (dtin|Bm|Cm zero)
__global__ void prep_kernel(const float* __restrict__ x, const float* __restrict__ ln_g,
                            const float* __restrict__ ln_b,
                            const float* __restrict__ w_in, const float* __restrict__ dtin_w,
                            const float* __restrict__ B_w, const float* __restrict__ C_w,
                            const float* __restrict__ dt_w, const float* __restrict__ out_w,
                            __hip_bfloat16* __restrict__ w1b, __hip_bfloat16* __restrict__ wpb,
                            __hip_bfloat16* __restrict__ dtwb, __hip_bfloat16* __restrict__ owb,
                            __hip_bfloat16* __restrict__ xn, float* __restrict__ zblock)
{
    const int b = blockIdx.x;
    const int tid = threadIdx.x;
    if (b < MR) {  // layernorm row b
        const float4 v = ((const float4*)(x + (size_t)b * DMOD))[tid];
        float s  = v.x + v.y + v.z + v.w;
        float sq = v.x * v.x + v.y * v.y + v.z * v.z + v.w * v.w;
#pragma unroll
        for (int off = 32; off >= 1; off >>= 1) {
            s  += __shfl_down(s, off, 64);
            sq += __shfl_down(sq, off, 64);
        }
        __shared__ float red[8];
        const int w = tid >> 6, lane = tid & 63;
        if (lane == 0) { red[w] = s; red[4 + w] = sq; }
        __syncthreads();
        s  = red[0] + red[1] + red[2] + red[3];
        sq = red[4] + red[5] + red[6] + red[7];
        const float mean = s * (1.f / DMOD);
        const float rstd = rsqrtf(sq * (1.f / DMOD) - mean * mean + 1e-5f);
        const int col = tid * 4;
        const float vv[4] = {v.x, v.y, v.z, v.w};
#pragma unroll
        for (int i = 0; i < 4; i++)
            xn[(size_t)b * DMOD + col + i] =
                __float2bfloat16((vv[i] - mean) * rstd * ln_g[col + i] + ln_b[col + i]);
        return;
    }
    const int nb = gridDim.x - MR;
    for (int v4 = (b - MR) * 256 + tid; v4 < NCVT + NZR; v4 += nb * 256) {
        if (v4 >= NCVT) {
            float4 z; z.x = z.y = z.z = z.w = 0.f;
            ((float4*)zblock)[v4 - NCVT] = z;
            continue;
        }
        const int i = v4 * 4;
        const float* s; __hip_bfloat16* dk;
        if      (i < 4194304) { s = w_in   + i;             dk = w1b  + i; }
        else if (i < 4325376) { s = dtin_w + (i - 4194304); dk = wpb  + (i - 4194304); }
        else if (i < 4358144) { s = B_w    + (i - 4325376); dk = wpb  + 131072 + (i - 4325376); }
        else if (i < 4390912) { s = C_w    + (i - 4358144); dk = wpb  + 163840 + (i - 4358144); }
        else if (i < 4521984) { s = dt_w   + (i - 4390912); dk = dtwb + (i - 4390912); }
        else                  { s = out_w  + (i - 4521984); dk = owb  + (i - 4521984); }
        const float4 f = *(const float4*)s;
        ushort4 o;
        o.x = (unsigned short)(__hip_bfloat16_raw(__float2bfloat16(f.x)).x);
        o.y = (unsigned short)(__hip_bfloat16_raw(__float2bfloat16(f.y)).x);
        o.z = (unsigned short)(__hip_bfloat16_raw(__float2bfloat16(f.z)).x);
        o.w = (unsigned short)(__hip_bfloat16_raw(__float2bfloat16(f.w)).x);
        *(ushort4*)dk = o;
    }
}

// ===================== chunked selective scan =====================
// R20: block = 64 d-cols x 4 nh (4 states/thread), 2048 blocks (8/CU), 20KB LDS.
// blk = bb*1024 + c*32 + dtile; d0 = dtile*64.
// p1 computes dt in an MFMA preamble (R19 numerics) -> sDT + coalesced dtb flush.

__global__ __launch_bounds__(256) void scan_p1(
    const float* __restrict__ fdtin, const float* __restrict__ dtin_b,
    const __hip_bfloat16* __restrict__ dtwb, const float* __restrict__ dt_b,
    const __hip_bfloat16* __restrict__ u,
    const float* __restrict__ Bm, const float* __restrict__ A_log,
    float* __restrict__ Aprod, float* __restrict__ Bacc,
    __hip_bfloat16* __restrict__ dtb)
{
    __shared__ float sB[TCH * NST];
    __shared__ __align__(16) __hip_bfloat16 sDT[TCH * 64];
    __shared__ __align__(16) __hip_bfloat16 sU [TCH * 64];
    const int blk = blockIdx.x;
    const int bb = blk >> 10, c = (blk >> 5) & 31, dtile = blk & 31;
    const int tid = threadIdx.x;
    const int nh = tid & 3, dl = tid >> 2;     // dl 0..63
    const int d = dtile * 64 + dl;
    const int d0 = dtile * 64;
    const int row0 = bb * LSEQ + c * TCH;
    const int wv = tid >> 6, lane = tid & 63;
    const int lrow = lane & 15, lq = lane >> 4;

    {   // DMA-stage u tile: 32 rows x 64 cols (128B/row), one pass
        const int r = tid >> 3, cq = (tid & 7) * 8;
        const __hip_bfloat16* gu = u + (size_t)row0 * DIN + d0;
        glds16(gu + (size_t)r * DIN + cq, &sU[r * 64 + cq]);
    }
    sB[tid]       = Bm[(size_t)row0 * NST + tid];
    sB[tid + 256] = Bm[(size_t)row0 * NST + tid + 256];

    // ---- dt preamble (R19/R20): 32t x 64d tile, wave wv -> mt=wv>>1, nt pair
    {
        const int mt = wv >> 1;
        const int ng = (wv & 1) * 2;
        f32x4 dacc[2];
#pragma unroll
        for (int nt = 0; nt < 2; nt++) { dacc[nt][0]=0.f; dacc[nt][1]=0.f; dacc[nt][2]=0.f; dacc[nt][3]=0.f; }
#pragma unroll
        for (int s = 0; s < 2; s++) {   // K=64 in 2 x K=32
            const float* ap = fdtin + (size_t)(row0 + mt * 16 + lrow) * 64 + s * 32 + lq * 8;
            const float4 f0 = *(const float4*)ap;
            const float4 f1 = *(const float4*)(ap + 4);
            const float4 b0 = *(const float4*)&dtin_b[s * 32 + lq * 8];
            const float4 b1 = *(const float4*)&dtin_b[s * 32 + lq * 8 + 4];
            bf16x8 afr;
            afr[0] = f2b(f0.x + b0.x); afr[1] = f2b(f0.y + b0.y);
            afr[2] = f2b(f0.z + b0.z); afr[3] = f2b(f0.w + b0.w);
            afr[4] = f2b(f1.x + b1.x); afr[5] = f2b(f1.y + b1.y);
            afr[6] = f2b(f1.z + b1.z); afr[7] = f2b(f1.w + b1.w);
#pragma unroll
            for (int nt = 0; nt < 2; nt++) {
                const bf16x8 bfr = *(const bf16x8*)&dtwb[(size_t)(d0 + (ng + nt) * 16 + lrow) * 64 + s * 32 + lq * 8];
                dacc[nt] = __builtin_amdgcn_mfma_f32_16x16x32_bf16(afr, bfr, dacc[nt], 0, 0, 0);
            }
        }
        // C layout: row=lq*4+r, col=lrow -> t = mt*16+lq*4+r, dloc = (ng+nt)*16+lrow
#pragma unroll
        for (int nt = 0; nt < 2; nt++) {
            const int dloc = (ng + nt) * 16 + lrow;
            const float db = dt_b[d0 + dloc];
#pragma unroll
            for (int r = 0; r < 4; r++) {
                const float xx = dacc[nt][r] + db;
                const float sp = (xx > 20.f) ? xx : log1pf(__expf(xx));
                sDT[(mt * 16 + lq * 4 + r) * 64 + dloc] = __float2bfloat16(sp);
            }
        }
    }

    float a2[4];
    {
        const float4 al = *(const float4*)&A_log[(size_t)d * NST + nh * 4];
        a2[0] = -__expf(al.x) * LOG2E; a2[1] = -__expf(al.y) * LOG2E;
        a2[2] = -__expf(al.z) * LOG2E; a2[3] = -__expf(al.w) * LOG2E;
    }
    __syncthreads();   // drains glds16 DMA + sB/sDT stores

    {   // coalesced dtb flush for p3: one 16B pass
        const int r = tid >> 3, cq = (tid & 7) * 8;
        __hip_bfloat16* gdt = dtb + (size_t)row0 * DIN + d0;
        *(bf16x8*)(gdt + (size_t)r * DIN + cq) = *(const bf16x8*)&sDT[r * 64 + cq];
    }

    float h[4], Ap[4];
#pragma unroll
    for (int j = 0; j < 4; j++) { h[j] = 0.f; Ap[j] = 1.f; }

#pragma unroll 4
    for (int t = 0; t < TCH; t++) {
        const float dtv = __bfloat162float(sDT[t * 64 + dl]);
        const float uv  = __bfloat162float(sU [t * 64 + dl]);
        const float du = dtv * uv;
        float bv[4];
        *(float4*)&bv[0] = *(const float4*)&sB[t * NST + nh * 4];
#pragma unroll
        for (int j = 0; j < 4; j++) {
            const float e = EXP2F(dtv * a2[j]);
            Ap[j] *= e;
            h[j] = h[j] * e + du * bv[j];
        }
    }
    const size_t idx = (((size_t)bb * CCH + c) * DIN + d) * NST + nh * 4;
    *(float4*)&Aprod[idx] = make_float4(Ap[0], Ap[1], Ap[2], Ap[3]);
    *(float4*)&Bacc[idx]  = make_float4(h[0], h[1], h[2], h[3]);
}

// p2: inter-chunk serial chain. Prefetch ALL (Aprod,Bacc) pairs into registers
// (independent loads, one latency), then the CCH-long FMA chain + stores.
__global__ __launch_bounds__(256) void scan_p2(
    const float* __restrict__ Aprod, const float* __restrict__ Bacc,
    float* __restrict__ hstart)
{
    const int i = blockIdx.x * 256 + threadIdx.x;
    const int bb = i >> 15;          // DIN*NST = 32768 per batch
    const int dn = i & 32767;
    const size_t base = (((size_t)bb * CCH) << 15) + dn;
    float ap[CCH], bc[CCH];
#pragma unroll
    for (int c = 0; c < CCH; c++) {
        ap[c] = Aprod[base + ((size_t)c << 15)];
        bc[c] = Bacc[base + ((size_t)c << 15)];
    }
    float hs = 0.f;
#pragma unroll
    for (int c = 0; c < CCH; c++) {
        hstart[base + ((size_t)c << 15)] = hs;
        hs = fmaf(ap[c], hs, bc[c]);
    }
}

__global__ __launch_bounds__(256) void scan_p3(
    const __hip_bfloat16* __restrict__ dt, const __hip_bfloat16* __restrict__ u,
    const float* __restrict__ Bm, const float* __restrict__ Cm,
    const float* __restrict__ A_log, const float* __restrict__ Dp,
    const __hip_bfloat16* __restrict__ zs, const float* __restrict__ hstart,
    __hip_bfloat16* __restrict__ y)
{
    __shared__ float sB[TCH * NST], sC[TCH * NST];
    __shared__ __align__(16) __hip_bfloat16 sDT[TCH * 64];
    __shared__ __align__(16) __hip_bfloat16 sU [TCH * 64];
    __shared__ __align__(16) __hip_bfloat16 sZ [TCH * 64];
    __shared__ __align__(16) __hip_bfloat16 sY [TCH * 64];
    const int blk = blockIdx.x;
    const int bb = blk >> 10, c = (blk >> 5) & 31, dtile = blk & 31;
    const int tid = threadIdx.x;
    const int nh = tid & 3, dl = tid >> 2;     // dl 0..63
    const int d = dtile * 64 + dl;
    const int d0 = dtile * 64;
    const int row0 = bb * LSEQ + c * TCH;

    {   // DMA-stage dt/u/z tiles: 32 rows x 64 cols, one pass each
        const int r = tid >> 3, cq = (tid & 7) * 8;
        const __hip_bfloat16* gdt = dt + (size_t)row0 * DIN + d0;
        const __hip_bfloat16* gu  = u  + (size_t)row0 * DIN + d0;
        const __hip_bfloat16* gz  = zs + (size_t)row0 * DIN + d0;
        glds16(gdt + (size_t)r * DIN + cq, &sDT[r * 64 + cq]);
        glds16(gu  + (size_t)r * DIN + cq, &sU [r * 64 + cq]);
        glds16(gz  + (size_t)r * DIN + cq, &sZ [r * 64 + cq]);
    }
    sB[tid]       = Bm[(size_t)row0 * NST + tid];
    sB[tid + 256] = Bm[(size_t)row0 * NST + tid + 256];
    sC[tid]       = Cm[(size_t)row0 * NST + tid];
    sC[tid + 256] = Cm[(size_t)row0 * NST + tid + 256];

    float a2[4];
    {
        const float4 al = *(const float4*)&A_log[(size_t)d * NST + nh * 4];
        a2[0] = -__expf(al.x) * LOG2E; a2[1] = -__expf(al.y) * LOG2E;
        a2[2] = -__expf(al.z) * LOG2E; a2[3] = -__expf(al.w) * LOG2E;
    }
    const float Dd = Dp[d];
    const size_t idx = (((size_t)bb * CCH + c) * DIN + d) * NST + nh * 4;
    float h[4];
    *(float4*)&h[0] = *(const float4*)&hstart[idx];
    __syncthreads();   // drains glds16 DMAs + sB/sC stores

#pragma unroll 4
    for (int t = 0; t < TCH; t++) {
        const float dtv = __bfloat162float(sDT[t * 64 + dl]);
        const float uv  = __bfloat162float(sU [t * 64 + dl]);
        const float du = dtv * uv;
        float bv[4], cv[4];
        *(float4*)&bv[0] = *(const float4*)&sB[t * NST + nh * 4];
        *(float4*)&cv[0] = *(const float4*)&sC[t * NST + nh * 4];
        float yp = 0.f;
#pragma unroll
        for (int j = 0; j < 4; j++) {
            const float e = EXP2F(dtv * a2[j]);
            h[j] = h[j] * e + du * bv[j];
            yp += h[j] * cv[j];
        }
        yp += __shfl_xor(yp, 1, 64);
        yp += __shfl_xor(yp, 2, 64);
        if (nh == 0) {
            const float zv = __bfloat162float(sZ[t * 64 + dl]);
            sY[t * 64 + dl] = __float2bfloat16((yp + uv * Dd) * zv);
        }
    }
    __syncthreads();
    {   // coalesced y flush: one 16B pass
        const int r = tid >> 3, cq = (tid & 7) * 8;
        __hip_bfloat16* gy = y + (size_t)row0 * DIN + d0;
        *(bf16x8*)(gy + (size_t)r * DIN + cq) = *(const bf16x8*)&sY[r * 64 + cq];
    }
}

extern "C" void kernel_launch(void* const* d_in, const int* in_sizes, int n_in,
                              void* d_out, int out_size, void* d_ws, size_t ws_size,
                              hipStream_t stream) {
    const float* x      = (const float*)d_in[0];
    const float* ln_g   = (const float*)d_in[1];
    const float* ln_b   = (const float*)d_in[2];
    const float* w_in   = (const float*)d_in[3];   // (4096,1024)
    const float* conv_w = (const float*)d_in[4];   // (2048,1,4)
    const float* conv_b = (const float*)d_in[5];
    const float* dtin_w = (const float*)d_in[6];   // (64,2048)
    const float* dtin_b = (const float*)d_in[7];
    const float* dt_w   = (const float*)d_in[8];   // (2048,64)
    const float* dt_b   = (const float*)d_in[9];
    const float* B_w    = (const float*)d_in[10];  // (16,2048)
    const float* C_w    = (const float*)d_in[11];
    const float* A_log  = (const float*)d_in[12];  // (2048,16)
    const float* Dp     = (const float*)d_in[13];
    const float* out_w  = (const float*)d_in[14];  // (1024,2048)
    float* out = (float*)d_out;

    char* ws = (char*)d_ws;
    auto alloc = [&](size_t bytes) { char* p = ws; ws += (bytes + 255) & ~255ull; return p; };
    __hip_bfloat16* w1b   = (__hip_bfloat16*)alloc((size_t)4096 * 1024 * 2);   // R18: wpb MUST
    __hip_bfloat16* wpb   = (__hip_bfloat16*)alloc((size_t)96 * 2048 * 2);     // follow w1b
    __hip_bfloat16* dtwb  = (__hip_bfloat16*)alloc((size_t)2048 * 64 * 2);
    __hip_bfloat16* owb   = (__hip_bfloat16*)alloc((size_t)1024 * 2048 * 2);
    __hip_bfloat16* xnb   = (__hip_bfloat16*)alloc((size_t)MR * DMOD * 2);
    __hip_bfloat16* zs    = (__hip_bfloat16*)alloc((size_t)MR * DIN * 2);
    __hip_bfloat16* xcb   = (__hip_bfloat16*)alloc((size_t)MR * DIN * 2);
    __hip_bfloat16* dtb   = (__hip_bfloat16*)alloc((size_t)MR * DIN * 2);
    __hip_bfloat16* yb    = (__hip_bfloat16*)alloc((size_t)MR * DIN * 2);
    float*          zblock= (float*)alloc((size_t)196608 * 4);    // dtin|Bm|Cm (zeroed by prep)
    float*          Aprod = (float*)alloc((size_t)BL * CCH * DIN * NST * 4);
    float*          Bacc  = (float*)alloc((size_t)BL * CCH * DIN * NST * 4);
    float*          hstart= (float*)alloc((size_t)BL * CCH * DIN * NST * 4);

    float* fdtin = zblock;            // 2048 x 64
    float* Bmf   = zblock + 131072;   // 2048 x 16 ; Cmf = Bmf + 32768 (contiguous)
    float* Cmf   = Bmf + (size_t)MR * NST;

    // 1. prep: weight conversions + layernorm + zero accum (one dispatch)
    prep_kernel<<<MR + 896, 256, 0, stream>>>(x, ln_g, ln_b, w_in, dtin_w, B_w, C_w, dt_w,
                                              out_w, w1b, wpb, dtwb, owb, xnb, zblock);

    // 2. in_proj + fused conv+silu + fused [dtin|Bm|Cm] projection (R18):
    //    (2048 x 4096), K=1024 — 1024 blocks; zblock passed via Af.
    gemm_bt<0, 64, 128, 64><<<dim3(32, 32, 1), 256, 0, stream>>>(
        xnb, 1024, w1b, 1024, MR, 4096, 1024, xcb, zs, conv_w, conv_b, zblock);

    // 3-5. chunked selective scan (R20: 2048 blocks, 4 states/thread)
    scan_p1<<<BL * CCH * 32, 256, 0, stream>>>(fdtin, dtin_b, dtwb, dt_b,
                                               xcb, Bmf, A_log, Aprod, Bacc, dtb);
    scan_p2<<<BL * DIN * NST / 256, 256, 0, stream>>>(Aprod, Bacc, hstart);
    scan_p3<<<BL * CCH * 32, 256, 0, stream>>>(dtb, xcb, Bmf, Cmf,
                                               A_log, Dp, zs, hstart, yb);

    // 6. out = y @ out_w^T + residual : (2048 x 1024), K=2048, BK=128 (R22)
    //    — 512 blocks, 16 K-steps (barrier count halved vs BK=64).
    gemm_bt<3, 64, 64, 128><<<dim3(16, 32, 1), 256, 0, stream>>>(
        yb, 2048, owb, 2048, MR, DMOD, 2048, out, (void*)x, nullptr, nullptr, nullptr);
}